// Round 17
// baseline (544.035 us; speedup 1.0000x reference)
//
#include <hip/hip_runtime.h>
#include <cstdint>
#include <cstddef>

#define N_NEU 2048
#define D_IN  1024
#define T_STEPS 64

typedef _Float16 f16x8 __attribute__((ext_vector_type(8)));
typedef _Float16 f16x4 __attribute__((ext_vector_type(4)));
typedef float    f32x4 __attribute__((ext_vector_type(4)));
typedef float    f32x16 __attribute__((ext_vector_type(16)));
typedef unsigned u32x4 __attribute__((ext_vector_type(4)));

#define MFMA32(a, b, c) __builtin_amdgcn_mfma_f32_32x32x16_f16((a), (b), (c), 0, 0, 0)

// ---------------- ws layout (bytes) ----------------
// Wh   [2048][2048] f16   @ 0       (8 MB)
// Wl   [2048][2048] f16   @ 8 MB    (8 MB)
// Iext [256][2048]  f32   @ 16 MB   (2 MB)
// bmv  u64[2][64][256]    @ 18 MB   (256 KB)  TRANSPOSED: [buf][colword][row],
//                                    u64 = (tag<<32) | 32 spike bits (cols w*32..+32)

// 8 bits -> 8 f16 (0.0/1.0) via multiply-spread: 4 VALU/word.
__device__ inline f16x8 expand8(unsigned b) {
  u32x4 t;
#pragma unroll
  for (int i = 0; i < 4; ++i) {
    unsigned m = (b >> (2 * i)) & 3u;
    unsigned s = (m | (m << 15)) & 0x00010001u;
    t[i] = s * 0x3C00u;
  }
  return __builtin_bit_cast(f16x8, t);
}

// Split W_eff = adj*mask into f16 hi + f16 lo' (w ~= hi + lo'/4096). Zeroes bmv (replay!).
__global__ __launch_bounds__(256) void k_wsplit(const float* __restrict__ adj,
                                                const float* __restrict__ mask,
                                                _Float16* __restrict__ Wh,
                                                _Float16* __restrict__ Wl,
                                                unsigned long long* __restrict__ bmv) {
  const int idx = blockIdx.x * 256 + threadIdx.x;
  if (idx < 2 * 64 * 256) bmv[idx] = 0ull;
  const int total4 = (N_NEU * N_NEU) / 4;
  for (int i = idx; i < total4; i += gridDim.x * 256) {
    float4 a = ((const float4*)adj)[i];
    float4 m = ((const float4*)mask)[i];
    float w0 = a.x * m.x, w1 = a.y * m.y, w2 = a.z * m.z, w3 = a.w * m.w;
    f16x4 h, lo;
    h[0] = (_Float16)w0; lo[0] = (_Float16)((w0 - (float)h[0]) * 4096.0f);
    h[1] = (_Float16)w1; lo[1] = (_Float16)((w1 - (float)h[1]) * 4096.0f);
    h[2] = (_Float16)w2; lo[2] = (_Float16)((w2 - (float)h[2]) * 4096.0f);
    h[3] = (_Float16)w3; lo[3] = (_Float16)((w3 - (float)h[3]) * 4096.0f);
    ((f16x4*)Wh)[i] = h;
    ((f16x4*)Wl)[i] = lo;
  }
}

// I_ext = ext @ W_in^T + b_in, plain fp32. Proven absmax 0.0 (r1/r5-r16).
__global__ __launch_bounds__(256) void k_iext(const float* __restrict__ ext,
                                              const float* __restrict__ Win,
                                              const float* __restrict__ bin,
                                              float* __restrict__ Iext) {
  __shared__ float At[32][68];
  __shared__ float Bt[32][68];
  const int tid = threadIdx.x;
  const int b0 = (blockIdx.x & 3) * 64;
  const int n0 = (blockIdx.x >> 2) * 64;
  const int tx = tid & 15, ty = tid >> 4;
  float acc[4][4] = {};
  for (int kt = 0; kt < D_IN / 32; ++kt) {
    const int k0 = kt * 32;
#pragma unroll
    for (int i = 0; i < 8; ++i) {
      int e = tid + i * 256;
      int kk = e & 31, row = e >> 5;
      At[kk][row] = ext[(size_t)(b0 + row) * D_IN + k0 + kk];
      Bt[kk][row] = Win[(size_t)(n0 + row) * D_IN + k0 + kk];
    }
    __syncthreads();
    for (int kk = 0; kk < 32; ++kk) {
      f32x4 a = *(const f32x4*)&At[kk][ty * 4];
      f32x4 b = *(const f32x4*)&Bt[kk][tx * 4];
#pragma unroll
      for (int i = 0; i < 4; ++i)
#pragma unroll
        for (int j = 0; j < 4; ++j) acc[i][j] += a[i] * b[j];
    }
    __syncthreads();
  }
#pragma unroll
  for (int i = 0; i < 4; ++i)
#pragma unroll
    for (int j = 0; j < 4; ++j)
      Iext[(size_t)(b0 + ty * 4 + i) * N_NEU + n0 + tx * 4 + j] = acc[i][j] + bin[n0 + tx * 4 + j];
}

// Persistent fused LIF kernel: wave-autonomous zero-barrier dataflow.
// 256 blocks x 512 thr (1/CU). Block (gp 0..3, ns 0..63): groups gA=gp, gB=gp+4 (32 rows)
// x cols ns*32..+32. 8 waves split K (256 each). 32x32x16 MFMA; Wh+Wl resident.
// Transposed bitmap: each wave loads/checks ONLY its own K-slice words (no LDS staging,
// no stage sync). K-slot bijection k = kw*256 + (hl*16+kcl)*8 + reg applied consistently
// to A (register bytes) and B (resident-W base) -> identical dot products.
__global__ __launch_bounds__(512, 2) void k_fused14(
    const _Float16* __restrict__ Wh, const _Float16* __restrict__ Wl,
    const float* __restrict__ Iext, unsigned long long* __restrict__ bmv,
    float* __restrict__ out) {
  __shared__ float red[2][8 * 32 * 33];  // 2 x 33 KB ping-pong split-K reduce

  const int tid = threadIdx.x;
  const int lane = tid & 63;
  const int kw = tid >> 6;        // wave id = split-K index 0..7
  const int l31 = lane & 31;
  const int hl = lane >> 5;       // 0/1
  const int gp = blockIdx.x >> 6; // 0..3
  const int ns = blockIdx.x & 63; // 0..63
  const int n0 = ns * 32;
  const int gA = gp, gB = gp + 4;
  const float inv4096 = 1.0f / 4096.0f;

  // ---------- per-thread Iext (mapping identical to r16) ----------
  float IxA[2], IxB[2];
#pragma unroll
  for (int j = 0; j < 2; ++j) {
    IxA[j] = Iext[(size_t)(gA * 32 + j * 16 + (tid >> 5)) * N_NEU + n0 + (tid & 31)];
    IxB[j] = Iext[(size_t)(gB * 32 + j * 16 + (tid >> 5)) * N_NEU + n0 + (tid & 31)];
  }

  // ---------- resident Wh + Wl fragments under the k-remap ----------
  // B lane (col=l31, hl): whf[kcl][reg] = W[n0+l31][kw*256 + hl*128 + kcl*8 + reg]
  const _Float16* whb = Wh + (size_t)(n0 + l31) * N_NEU + kw * 256 + hl * 128;
  const _Float16* wlb = Wl + (size_t)(n0 + l31) * N_NEU + kw * 256 + hl * 128;
  f16x8 whf[16], wlf[16];
#pragma unroll
  for (int kcl = 0; kcl < 16; ++kcl) {
    whf[kcl] = *(const f16x8*)(whb + kcl * 8);
    wlf[kcl] = *(const f16x8*)(wlb + kcl * 8);
  }

  float VA[2] = {0.f, 0.f}, VB[2] = {0.f, 0.f};
  unsigned cA[2] = {0u, 0u}, cB[2] = {0u, 0u};
  unsigned long long vA[4], vB[4];

  // wave-autonomous speculative load: thread's 4 words = its own K-slice bytes
  // word w = kw*8 + hl*4 + i (u64-colword), row = gp*64 + g*32 + l31
  auto spec_issue = [&](int g, int buf, unsigned long long (&v)[4]) {
    const unsigned long long* src =
        bmv + (size_t)buf * 16384 + (size_t)(kw * 8 + hl * 4) * 256 + gp * 64 + g * 32 + l31;
#pragma unroll
    for (int i = 0; i < 4; ++i)
      v[i] = __hip_atomic_load(src + (size_t)i * 256, __ATOMIC_RELAXED, __HIP_MEMORY_SCOPE_AGENT);
  };
  // validate tags on own slice only; retry stale words
  auto check_retry = [&](int g, int buf, unsigned want, unsigned long long (&v)[4]) {
    const unsigned long long* src =
        bmv + (size_t)buf * 16384 + (size_t)(kw * 8 + hl * 4) * 256 + gp * 64 + g * 32 + l31;
    unsigned need = 0u;
#pragma unroll
    for (int i = 0; i < 4; ++i)
      if ((unsigned)(v[i] >> 32) != want) need |= 1u << i;
    while (need) {
      __builtin_amdgcn_s_sleep(1);
#pragma unroll
      for (int i = 0; i < 4; ++i)
        if (need & (1u << i)) {
          v[i] = __hip_atomic_load(src + (size_t)i * 256,
                                   __ATOMIC_RELAXED, __HIP_MEMORY_SCOPE_AGENT);
          if ((unsigned)(v[i] >> 32) == want) need &= ~(1u << i);
        }
    }
  };
  // K-loop (32 MFMA) + flat 8-slab split-K tree (ONE sync, ping-pong red) -> cI[2]
  auto gemm = [&](const unsigned long long (&v)[4], float* redb, float (&cI)[2]) {
    unsigned q[4];
#pragma unroll
    for (int i = 0; i < 4; ++i) q[i] = (unsigned)v[i];
    f32x16 acch = {0.f, 0.f, 0.f, 0.f, 0.f, 0.f, 0.f, 0.f,
                   0.f, 0.f, 0.f, 0.f, 0.f, 0.f, 0.f, 0.f};
    f32x16 accl = acch;
    __builtin_amdgcn_s_setprio(1);
#pragma unroll
    for (int kcl = 0; kcl < 16; ++kcl) {
      // A byte kcl of this thread's 16 held bytes (k = kw*256 + (hl*16+kcl)*8 + reg)
      const f16x8 a = expand8((q[kcl >> 2] >> ((kcl & 3) * 8)) & 0xFFu);
      acch = MFMA32(a, whf[kcl], acch);
      accl = MFMA32(a, wlf[kcl], accl);
    }
    __builtin_amdgcn_s_setprio(0);
    f32x16 cb = acch + accl * inv4096;
    // C layout: col = lane&31, row = (reg&3) + 8*(reg>>2) + 4*hl
    const int hl4 = hl * 4;
#pragma unroll
    for (int rg = 0; rg < 4; ++rg) {
      f32x4 part = {cb[rg * 4 + 0], cb[rg * 4 + 1], cb[rg * 4 + 2], cb[rg * 4 + 3]};
      *(f32x4*)&redb[(kw * 32 + l31) * 33 + rg * 8 + hl4] = part;
    }
    __syncthreads();
#pragma unroll
    for (int j = 0; j < 2; ++j) {
      const int o = j * 512 + tid;
      const int row = o >> 5, col = o & 31;
      float s = 0.0f;
#pragma unroll
      for (int p = 0; p < 8; ++p) s += redb[(p * 32 + col) * 33 + row];
      cI[j] = s;
    }
  };
  // LIF + tagged spike stores to transposed layout: [nbuf][ns][row]
  auto lif = [&](const float (&cI)[2], const float (&Ix)[2], float (&V)[2],
                 unsigned (&cnt)[2], int g, int nbuf, unsigned tag, bool dostore) {
#pragma unroll
    for (int j = 0; j < 2; ++j) {
      float I = cI[j] + Ix[j];
      float v = 0.9f * V[j] + I;
      bool sp = (v - 1.0f) >= 0.0f;
      V[j] = sp ? 0.0f : v;
      cnt[j] += sp ? 1u : 0u;
      if (dostore) {
        unsigned long long ba = __ballot(sp);
        const int rowf = gp * 64 + g * 32 + j * 16 + kw * 2;  // global row; lanes0-31: rowf
        const unsigned long long tg = ((unsigned long long)tag) << 32;
        unsigned long long* dst = bmv + (size_t)nbuf * 16384 + (size_t)ns * 256;
        if (lane == 0)
          __hip_atomic_store(dst + rowf, tg | (unsigned)ba,
                             __ATOMIC_RELAXED, __HIP_MEMORY_SCOPE_AGENT);
        else if (lane == 32)
          __hip_atomic_store(dst + rowf + 1, tg | (unsigned)(ba >> 32),
                             __ATOMIC_RELAXED, __HIP_MEMORY_SCOPE_AGENT);
      }
    }
  };

  // ---------- t = 0: Iext-only LIF; spikes tagged 1 -> buf 1; prefetch A ----------
  {
    const float cz[2] = {0.f, 0.f};
    lif(cz, IxA, VA, cA, 0, 1, 1u, true);   // g index: 0 -> rows gp*64..+32 (group A)
    lif(cz, IxB, VB, cB, 1, 1, 1u, true);   // 1 -> rows gp*64+32..+64 (group B)
    spec_issue(0, 1, vA);
  }

  for (int t = 1; t < T_STEPS; ++t) {
    const int cbuf = t & 1, nbuf = (t + 1) & 1;
    const bool last = (t == T_STEPS - 1);
    float cI[2];

    // ---- phase A (rows gp*64..+32) ----
    check_retry(0, cbuf, (unsigned)t, vA);
    spec_issue(1, cbuf, vB);             // in flight under gemm(A)
    gemm(vA, red[0], cI);
    lif(cI, IxA, VA, cA, 0, nbuf, (unsigned)(t + 1), !last);

    // ---- phase B (rows gp*64+32..+64) ----
    check_retry(1, cbuf, (unsigned)t, vB);
    if (!last) spec_issue(0, nbuf, vA);  // in flight under gemm(B)
    gemm(vB, red[1], cI);
    lif(cI, IxB, VB, cB, 1, nbuf, (unsigned)(t + 1), !last);
  }

  // ---------- write firing rates ----------
#pragma unroll
  for (int j = 0; j < 2; ++j) {
    const int rA = gA * 32 + j * 16 + (tid >> 5);
    const int rB = gB * 32 + j * 16 + (tid >> 5);
    out[(size_t)rA * N_NEU + n0 + (tid & 31)] = (float)cA[j] * 0.015625f;
    out[(size_t)rB * N_NEU + n0 + (tid & 31)] = (float)cB[j] * 0.015625f;
  }
}

extern "C" void kernel_launch(void* const* d_in, const int* in_sizes, int n_in,
                              void* d_out, int out_size, void* d_ws, size_t ws_size,
                              hipStream_t stream) {
  (void)in_sizes; (void)n_in; (void)out_size; (void)ws_size;
  const float* ext  = (const float*)d_in[0];
  const float* Win  = (const float*)d_in[1];
  const float* bin  = (const float*)d_in[2];
  const float* adj  = (const float*)d_in[3];
  const float* mask = (const float*)d_in[4];
  unsigned char* ws = (unsigned char*)d_ws;

  _Float16* Wh   = (_Float16*)(ws);
  _Float16* Wl   = (_Float16*)(ws + (size_t)(8u << 20));
  float*    Iext = (float*)   (ws + (size_t)(16u << 20));
  unsigned long long* bmv = (unsigned long long*)(ws + (size_t)(18u << 20));
  float* out = (float*)d_out;

  hipLaunchKernelGGL(k_wsplit, dim3(2048), dim3(256), 0, stream, adj, mask, Wh, Wl, bmv);
  hipLaunchKernelGGL(k_iext,   dim3(128),  dim3(256), 0, stream, ext, Win, bin, Iext);
  hipLaunchKernelGGL(k_fused14, dim3(256), dim3(512), 0, stream,
                     Wh, Wl, Iext, bmv, out);
}